// Round 5
// baseline (664.932 us; speedup 1.0000x reference)
//
#include <hip/hip_runtime.h>
#include <hip/hip_bf16.h>
#include <math.h>

#define B_ 4
#define S_ 1024
#define T_ (B_ * S_)      // 4096 tokens
#define D_ 1024
#define H_ 4096
#define E_ 8
#define K_ 2
#define A_ (T_ * K_)      // 8192 assignments
#define NTM_ 40           // max m-tiles at BM=256: 32 + 7 = 39 <= 40

typedef __bf16 bf16x8_t __attribute__((ext_vector_type(8)));
typedef float f32x4_t __attribute__((ext_vector_type(4)));
typedef unsigned short u16x8_t __attribute__((ext_vector_type(8)));

__device__ inline unsigned short f2bf(float f) {
    __hip_bfloat16 h = __float2bfloat16(f);
    return *reinterpret_cast<unsigned short*>(&h);
}

// fast GELU: A&S 7.1.26 erf poly, |err|~1e-5 absolute (bf16 quantum is 4e-3)
__device__ __forceinline__ float fast_gelu(float v) {
    float z = v * 0.70710678118654752440f;
    float az = fabsf(z);
    float t = __builtin_amdgcn_rcpf(1.0f + 0.3275911f * az);
    float poly = ((((1.061405429f * t - 1.453152027f) * t + 1.421413741f) * t
                   - 0.284496736f) * t + 0.254829592f) * t;
    float e = __expf(-az * az);
    float erfv = 1.0f - poly * e;
    erfv = (z < 0.0f) ? -erfv : erfv;
    return 0.5f * v * (1.0f + erfv);
}

// async global->LDS, 16B per lane. LDS dest = wave-uniform base + lane*16.
__device__ __forceinline__ void gl2lds16(const unsigned short* g, unsigned short* l) {
    auto* gp = reinterpret_cast<const __attribute__((address_space(1))) unsigned int*>(
        reinterpret_cast<uintptr_t>(g));
    auto* lp = reinterpret_cast<__attribute__((address_space(3))) unsigned int*>(
        reinterpret_cast<uintptr_t>(l));
    __builtin_amdgcn_global_load_lds(gp, lp, 16, 0, 0);
}

// ---------------- router ---------------------------------------------------
__global__ void router_kernel(const float* __restrict__ x, const float* __restrict__ rw,
                              int* __restrict__ tok_e, float* __restrict__ tok_w,
                              int* __restrict__ counts_pad, float* __restrict__ probs_pad) {
    __shared__ float s_probs[E_];
    __shared__ int s_counts[E_];
    const int tid = threadIdx.x;
    if (tid < E_) { s_probs[tid] = 0.f; s_counts[tid] = 0; }
    __syncthreads();
    const int wave = tid >> 6;
    const int lane = tid & 63;

    float wprob[E_];
    int wcount[E_];
#pragma unroll
    for (int e = 0; e < E_; ++e) { wprob[e] = 0.f; wcount[e] = 0; }

    for (int tt = 0; tt < 4; ++tt) {
        const int token = blockIdx.x * 16 + wave * 4 + tt;
        const float* xr = x + (long)token * D_;
        float acc[E_];
#pragma unroll
        for (int e = 0; e < E_; ++e) acc[e] = 0.f;
        for (int i = 0; i < D_ / 64; ++i) {
            int d = i * 64 + lane;
            float xv = xr[d];
            const float* w = rw + (long)d * E_;
#pragma unroll
            for (int e = 0; e < E_; ++e) acc[e] += xv * w[e];
        }
#pragma unroll
        for (int e = 0; e < E_; ++e) {
            for (int off = 32; off > 0; off >>= 1)
                acc[e] += __shfl_down(acc[e], off);
        }
        if (lane == 0) {
            float m = acc[0];
            for (int e = 1; e < E_; ++e) m = fmaxf(m, acc[e]);
            float p[E_], s = 0.f;
            for (int e = 0; e < E_; ++e) { p[e] = expf(acc[e] - m); s += p[e]; }
            float inv = 1.f / s;
            for (int e = 0; e < E_; ++e) { p[e] *= inv; wprob[e] += p[e]; }
            int i0 = 0;
            for (int e = 1; e < E_; ++e) if (p[e] > p[i0]) i0 = e;
            int i1 = (i0 == 0) ? 1 : 0;
            for (int e = 0; e < E_; ++e) if (e != i0 && p[e] > p[i1]) i1 = e;
            float w0 = p[i0], w1 = p[i1];
            float inv2 = 1.f / (w0 + w1 + 1e-8f);
            tok_e[token * 2] = i0;
            tok_e[token * 2 + 1] = i1;
            tok_w[token * 2] = w0 * inv2;
            tok_w[token * 2 + 1] = w1 * inv2;
            wcount[i0]++; wcount[i1]++;
        }
    }
    if (lane == 0) {
#pragma unroll
        for (int e = 0; e < E_; ++e) {
            atomicAdd(&s_probs[e], wprob[e]);
            if (wcount[e]) atomicAdd(&s_counts[e], wcount[e]);
        }
    }
    __syncthreads();
    if (tid < E_) {
        atomicAdd(&probs_pad[tid * 32], s_probs[tid]);
        if (s_counts[tid]) atomicAdd(&counts_pad[tid * 32], s_counts[tid]);
    }
}

// ------------- offsets + aux loss + compact tile table (BM=256) -----------
__global__ void offsets_aux_kernel(const int* __restrict__ counts_pad,
                                   const float* __restrict__ probs_pad,
                                   int* __restrict__ offsets,
                                   int* __restrict__ tile_e, int* __restrict__ tile_m,
                                   int* __restrict__ n_tiles, float* __restrict__ aux_out) {
    if (threadIdx.x == 0 && blockIdx.x == 0) {
        int run = 0, t = 0;
        for (int e = 0; e < E_; ++e) {
            int c = counts_pad[e * 32];
            offsets[e] = run;
            for (int m0 = 0; m0 < c; m0 += 256) {
                tile_e[t] = e; tile_m[t] = m0; ++t;
            }
            run += c;
        }
        offsets[E_] = run;
        *n_tiles = t;
        float aux = 0.f;
        for (int e = 0; e < E_; ++e)
            aux += (probs_pad[e * 32] / (float)T_) * ((float)counts_pad[e * 32] / (float)A_);
        *aux_out = (float)E_ * aux;
    }
}

// ---------------- scatter --------------------------------------------------
__global__ void scatter_kernel(const int* __restrict__ tok_e, const float* __restrict__ tok_w,
                               const int* __restrict__ offsets, int* __restrict__ cursors_pad,
                               int* __restrict__ perm_token, float* __restrict__ perm_weight,
                               int* __restrict__ inv_pos) {
    int i = blockIdx.x * blockDim.x + threadIdx.x;
    int lane = threadIdx.x & 63;
    int e = tok_e[i];
    float w = tok_w[i];
    unsigned long long bal[E_];
#pragma unroll
    for (int q = 0; q < E_; ++q) bal[q] = __ballot(e == q);
    unsigned long long below = (1ull << lane) - 1ull;
    int rank = __popcll(bal[e] & below);
    int base = 0;
    if (lane < E_) {
        int c = __popcll(bal[lane]);
        if (c) base = atomicAdd(&cursors_pad[lane * 32], c);
    }
    int mybase = __shfl(base, e);
    int pos = offsets[e] + mybase + rank;
    perm_token[pos] = i >> 1;
    perm_weight[pos] = w;
    inv_pos[i] = pos;
}

// ---------------- fp32 -> bf16 cast of x ----------------------------------
__global__ void cast_x_kernel(const float* __restrict__ x, unsigned short* __restrict__ xb) {
    long i = (long)blockIdx.x * blockDim.x + threadIdx.x;
    float4 v = reinterpret_cast<const float4*>(x)[i];
    unsigned long long packed = (unsigned long long)f2bf(v.x)
        | ((unsigned long long)f2bf(v.y) << 16)
        | ((unsigned long long)f2bf(v.z) << 32)
        | ((unsigned long long)f2bf(v.w) << 48);
    reinterpret_cast<unsigned long long*>(xb)[i] = packed;
}

// -------- fp32 [R][C] -> bf16 [C][R] per expert, vectorized both sides ----
__global__ void transpose_cast_kernel(const float* __restrict__ in, unsigned short* __restrict__ out,
                                      int R, int C) {
    __shared__ float tile[64][65];
    const long e = blockIdx.z;
    const float* in_e = in + e * (long)R * C;
    unsigned short* out_e = out + e * (long)R * C;
    const int c0 = blockIdx.x * 64;
    const int r0 = blockIdx.y * 64;
    const int tid = threadIdx.x;
    const int c4 = (tid & 15) * 4;
    const int rb = tid >> 4;
#pragma unroll
    for (int i = 0; i < 4; ++i) {
        const int r = rb + i * 16;
        const float4 v = *reinterpret_cast<const float4*>(&in_e[(long)(r0 + r) * C + c0 + c4]);
        tile[r][c4] = v.x; tile[r][c4 + 1] = v.y; tile[r][c4 + 2] = v.z; tile[r][c4 + 3] = v.w;
    }
    __syncthreads();
    const int rs = (tid & 7) * 8;
    const int cb = tid >> 3;
#pragma unroll
    for (int i = 0; i < 2; ++i) {
        const int c = cb + i * 32;
        u16x8_t p;
#pragma unroll
        for (int j = 0; j < 8; ++j) p[j] = f2bf(tile[rs + j][c]);
        *reinterpret_cast<u16x8_t*>(&out_e[(long)(c0 + c) * R + r0 + rs]) = p;
    }
}

// ---- grouped GEMM, m201-geometry: 256x256 tile, 512 thr (8 waves 2Mx4N, --
// ---- per-wave 128x64, acc 8x4), BK=64, LDS 128 KB = 2 dbuf x {A,B} x ----
// ---- 2 k-halves (k-half-major so gl_lds dest stays linear). 4 phases ----
// ---- per K-tile: {vmcnt(6); barrier; ds_read one half-tile; issue 2 -----
// ---- gl_lds of tile t+1's same half-tile; barrier; lgkmcnt(0); 16 MFMA}. -
// ---- MFMA runs one phase behind its operands (ph0 computes prev tile's --
// ---- last quadrant) -> reads/stages overlap MFMA; vmcnt never drains ----
// ---- mid-loop (6 loads = 3 half-tiles always in flight). ----------------
// FIFO guarantee: consume order == stage order (Ak0,Bk0,Ak1,Bk1), one
// half-tile per phase, so vmcnt(6)+barrier at each phase entry retires
// exactly the half-tile that phase reads (all waves, since each wave waits
// its own counter before the barrier). Last tile: vmcnt 6/4/2/0.
template <int PHASE, int NSPLIT>
__device__ __forceinline__ void gemm_body(const unsigned short* __restrict__ A_src,
                                const unsigned short* __restrict__ B_src,  // [E][N][K] bf16
                                const float* __restrict__ bias,            // [E][N]
                                const int* __restrict__ offsets,
                                const int* __restrict__ tile_e, const int* __restrict__ tile_m,
                                const int* __restrict__ p_ntiles,
                                const int* __restrict__ perm_token,
                                const float* __restrict__ perm_weight,
                                unsigned short* __restrict__ h_buf,
                                float* __restrict__ y_perm) {
    constexpr int Ksz  = (PHASE == 1) ? D_ : H_;
    constexpr int Kloc = Ksz / NSPLIT;
    constexpr int Nsz  = (PHASE == 1) ? H_ : D_;
    constexpr int NT   = Kloc / 64;                 // K-tiles (>= 16)
    constexpr int NTN  = Nsz / 256;

    // bijective XCD-chunked swizzle; mt fastest (B panel reuse in XCD L2)
    const int nwg = gridDim.x;
    const int id = blockIdx.x;
    const int q = nwg >> 3, r8 = nwg & 7;
    const int xcd = id & 7, sub = id >> 3;
    const int wg = (xcd < r8 ? xcd * (q + 1) : r8 * (q + 1) + (xcd - r8) * q) + sub;
    const int mt = wg % NTM_;
    if (mt >= *p_ntiles) return;
    const int rest = wg / NTM_;
    const int nt = rest % NTN;
    const int kh = rest / NTN;
    const int e = tile_e[mt];
    const int m0 = tile_m[mt];
    const int off_e = offsets[e];
    const int n_e = offsets[e + 1] - off_e;
    const int n0 = nt * 256;
    const long k_base = (long)kh * Kloc;

    // layout (shorts): [dbuf(16384)][khalf(8192)][row(32)][32], rows of 64B
    __shared__ __attribute__((aligned(16))) unsigned short lds_a[32768];
    __shared__ __attribute__((aligned(16))) unsigned short lds_b[32768];

    const int tid = threadIdx.x;
    const int lane = tid & 63;
    const int wave = tid >> 6;          // 0..7
    const int wr = wave >> 2;           // 0..1  (128-row strip)
    const int wc = wave & 3;            // 0..3  (64-col strip)
    const int lrow = lane & 15;
    const int kg = lane >> 4;

    // staging: per half-tile (256 rows x 32 k), wave w instr j covers rows
    // (j*8+w)*16..+15; lane: row +(lane>>2), 16B chunk lane&3, source chunk
    // XOR-swizzled by (row>>1)&3 = (lane>>3)&3.
    const int sc = (lane & 3) ^ ((lane >> 3) & 3);
    const unsigned short* gA[2];
    const unsigned short* gB[2];
    int st_off[2];
#pragma unroll
    for (int j = 0; j < 2; ++j) {
        const int rr = (j * 8 + wave) * 16 + (lane >> 2);
        const int m_loc = m0 + rr;
        const int m_cl = (m_loc < n_e) ? m_loc : (n_e - 1);
        const int pos = off_e + m_cl;
        long arow;
        if (PHASE == 1) arow = (long)perm_token[pos] * Ksz;
        else            arow = (long)pos * Ksz;
        gA[j] = A_src + arow + k_base + sc * 8;
        gB[j] = B_src + (long)e * Nsz * Ksz + (long)(n0 + rr) * Ksz + k_base + sc * 8;
        st_off[j] = (j * 8 + wave) * 512;
    }

    // ds_read bases (shorts); chunk swizzle kg ^ ((lrow>>1)&3) (2-way, free)
    const int rch = (kg ^ ((lrow >> 1) & 3)) * 8;
    const int a_rd = (wr * 128 + lrow) * 32 + rch;
    const int b_rd = (wc * 64 + lrow) * 32 + rch;

    f32x4_t acc[8][4];
#pragma unroll
    for (int i = 0; i < 8; ++i)
#pragma unroll
        for (int j = 0; j < 4; ++j) acc[i][j] = (f32x4_t){0.f, 0.f, 0.f, 0.f};

    bf16x8_t a0[8], a1[8], b0[4], b1[4];

    // prologue: tile 0 into dbuf 0, consume order Ak0,Bk0,Ak1,Bk1
    gl2lds16(gA[0], lds_a + st_off[0]);
    gl2lds16(gA[1], lds_a + st_off[1]);
    gl2lds16(gB[0], lds_b + st_off[0]);
    gl2lds16(gB[1], lds_b + st_off[1]);
    gl2lds16(gA[0] + 32, lds_a + 8192 + st_off[0]);
    gl2lds16(gA[1] + 32, lds_a + 8192 + st_off[1]);
    gl2lds16(gB[0] + 32, lds_b + 8192 + st_off[0]);
    gl2lds16(gB[1] + 32, lds_b + 8192 + st_off[1]);

    for (int t = 0; t < NT; ++t) {
        const int cur = (t & 1) << 14;
        const int nxt = 16384 - cur;
        const int toff = (t + 1) * 64;
        const bool pf = (t + 1 < NT);

        // ---------------- PH0: read A-k0; stage A-k0(t+1); MFMA prev k1 hi -
        asm volatile("s_waitcnt vmcnt(6)" ::: "memory");
        __builtin_amdgcn_s_barrier();
        asm volatile("" ::: "memory");
#pragma unroll
        for (int i = 0; i < 8; ++i)
            a0[i] = *reinterpret_cast<const bf16x8_t*>(lds_a + cur + a_rd + i * 512);
        if (pf) {
            gl2lds16(gA[0] + toff, lds_a + nxt + st_off[0]);
            gl2lds16(gA[1] + toff, lds_a + nxt + st_off[1]);
        }
        __builtin_amdgcn_s_barrier();
        asm volatile("s_waitcnt lgkmcnt(0)" ::: "memory");
        __builtin_amdgcn_sched_barrier(0);
        if (t > 0) {
            __builtin_amdgcn_s_setprio(1);
#pragma unroll
            for (int f = 0; f < 4; ++f)
#pragma unroll
                for (int j = 0; j < 4; ++j)
                    acc[4 + f][j] = __builtin_amdgcn_mfma_f32_16x16x32_bf16(
                        a1[4 + f], b1[j], acc[4 + f][j], 0, 0, 0);
            __builtin_amdgcn_s_setprio(0);
        }

        // ---------------- PH1: read B-k0; stage B-k0(t+1); MFMA k0 lo ------
        if (pf) asm volatile("s_waitcnt vmcnt(6)" ::: "memory");
        else    asm volatile("s_waitcnt vmcnt(4)" ::: "memory");
        __builtin_amdgcn_s_barrier();
        asm volatile("" ::: "memory");
#pragma unroll
        for (int j = 0; j < 4; ++j)
            b0[j] = *reinterpret_cast<const bf16x8_t*>(lds_b + cur + b_rd + j * 512);
        if (pf) {
            gl2lds16(gB[0] + toff, lds_b + nxt + st_off[0]);
            gl2lds16(gB[1] + toff, lds_b + nxt + st_off[1]);
        }
        __builtin_amdgcn_s_barrier();
        asm volatile("s_waitcnt lgkmcnt(0)" ::: "memory");
        __builtin_amdgcn_sched_barrier(0);
        __builtin_amdgcn_s_setprio(1);
#pragma unroll
        for (int f = 0; f < 4; ++f)
#pragma unroll
            for (int j = 0; j < 4; ++j)
                acc[f][j] = __builtin_amdgcn_mfma_f32_16x16x32_bf16(
                    a0[f], b0[j], acc[f][j], 0, 0, 0);
        __builtin_amdgcn_s_setprio(0);

        // ---------------- PH2: read A-k1; stage A-k1(t+1); MFMA k0 hi ------
        if (pf) asm volatile("s_waitcnt vmcnt(6)" ::: "memory");
        else    asm volatile("s_waitcnt vmcnt(2)" ::: "memory");
        __builtin_amdgcn_s_barrier();
        asm volatile("" ::: "memory");
#pragma unroll
        for (int i = 0; i < 8; ++i)
            a1[i] = *reinterpret_cast<const bf16x8_t*>(lds_a + cur + 8192 + a_rd + i * 512);
        if (pf) {
            gl2lds16(gA[0] + toff + 32, lds_a + nxt + 8192 + st_off[0]);
            gl2lds16(gA[1] + toff + 32, lds_a + nxt + 8192 + st_off[1]);
        }
        __builtin_amdgcn_s_barrier();
        asm volatile("s_waitcnt lgkmcnt(0)" ::: "memory");
        __builtin_amdgcn_sched_barrier(0);
        __builtin_amdgcn_s_setprio(1);
#pragma unroll
        for (int f = 0; f < 4; ++f)
#pragma unroll
            for (int j = 0; j < 4; ++j)
                acc[4 + f][j] = __builtin_amdgcn_mfma_f32_16x16x32_bf16(
                    a0[4 + f], b0[j], acc[4 + f][j], 0, 0, 0);
        __builtin_amdgcn_s_setprio(0);

        // ---------------- PH3: read B-k1; stage B-k1(t+1); MFMA k1 lo ------
        if (pf) asm volatile("s_waitcnt vmcnt(6)" ::: "memory");
        else    asm volatile("s_waitcnt vmcnt(0)" ::: "memory");
        __builtin_amdgcn_s_barrier();
        asm volatile("" ::: "memory");
#pragma unroll
        for (int j = 0; j < 4; ++j)
            b1[j] = *reinterpret_cast<const bf16x8_t*>(lds_b + cur + 8192 + b_rd + j * 512);
        if (pf) {
            gl2lds16(gB[0] + toff + 32, lds_b + nxt + 8192 + st_off[0]);
            gl2lds16(gB[1] + toff + 32, lds_b + nxt + 8192 + st_off[1]);
        }
        __builtin_amdgcn_s_barrier();
        asm volatile("s_waitcnt lgkmcnt(0)" ::: "memory");
        __builtin_amdgcn_sched_barrier(0);
        __builtin_amdgcn_s_setprio(1);
#pragma unroll
        for (int f = 0; f < 4; ++f)
#pragma unroll
            for (int j = 0; j < 4; ++j)
                acc[f][j] = __builtin_amdgcn_mfma_f32_16x16x32_bf16(
                    a1[f], b1[j], acc[f][j], 0, 0, 0);
        __builtin_amdgcn_s_setprio(0);
    }

    // drain: last tile's k1 x m-hi quadrant
    __builtin_amdgcn_s_setprio(1);
#pragma unroll
    for (int f = 0; f < 4; ++f)
#pragma unroll
        for (int j = 0; j < 4; ++j)
            acc[4 + f][j] = __builtin_amdgcn_mfma_f32_16x16x32_bf16(
                a1[4 + f], b1[j], acc[4 + f][j], 0, 0, 0);
    __builtin_amdgcn_s_setprio(0);

    // epilogue
    const float* bias_e = bias + (long)e * Nsz;
#pragma unroll
    for (int i = 0; i < 8; ++i) {
#pragma unroll
        for (int rq = 0; rq < 4; ++rq) {
            const int row_loc = wr * 128 + i * 16 + kg * 4 + rq;
            const int m_out = m0 + row_loc;
            if (m_out >= n_e) continue;
            const int pos = off_e + m_out;
            if (PHASE == 1) {
#pragma unroll
                for (int j = 0; j < 4; ++j) {
                    const int n = n0 + wc * 64 + j * 16 + lrow;
                    float v = acc[i][j][rq] + bias_e[n];
                    h_buf[(long)pos * Nsz + n] = f2bf(fast_gelu(v));
                }
            } else {
                float* yp = y_perm + (long)kh * ((long)A_ * D_);
                const float wgt = perm_weight[pos];
#pragma unroll
                for (int j = 0; j < 4; ++j) {
                    const int n = n0 + wc * 64 + j * 16 + lrow;
                    float v = acc[i][j][rq] + ((kh == 0) ? bias_e[n] : 0.f);
                    yp[(long)pos * Nsz + n] = v * wgt;
                }
            }
        }
    }
}

#define GEMM_ARGS const unsigned short* __restrict__ A_src, \
                  const unsigned short* __restrict__ B_src, \
                  const float* __restrict__ bias, \
                  const int* __restrict__ offsets, \
                  const int* __restrict__ tile_e, const int* __restrict__ tile_m, \
                  const int* __restrict__ p_ntiles, \
                  const int* __restrict__ perm_token, \
                  const float* __restrict__ perm_weight, \
                  unsigned short* __restrict__ h_buf, \
                  float* __restrict__ y_perm
#define GEMM_PASS A_src, B_src, bias, offsets, tile_e, tile_m, p_ntiles, \
                  perm_token, perm_weight, h_buf, y_perm

__launch_bounds__(512, 2)
__global__ void moe_gemm_p1(GEMM_ARGS) { gemm_body<1, 1>(GEMM_PASS); }
__launch_bounds__(512, 2)
__global__ void moe_gemm_p2s1(GEMM_ARGS) { gemm_body<2, 1>(GEMM_PASS); }
__launch_bounds__(512, 2)
__global__ void moe_gemm_p2s2(GEMM_ARGS) { gemm_body<2, 2>(GEMM_PASS); }
__launch_bounds__(512, 2)
__global__ void moe_gemm_p2s4(GEMM_ARGS) { gemm_body<2, 4>(GEMM_PASS); }

// ---------------- combine: out[t] = sum over splits and the 2 positions ---
__global__ void combine_kernel(const float* __restrict__ y_perm, const int* __restrict__ inv_pos,
                               float* __restrict__ out, int ns) {
    int t = blockIdx.x;
    int d4 = threadIdx.x;                 // 0..255, float4 index (D_/4 = 256)
    int p0 = inv_pos[t * 2];
    int p1 = inv_pos[t * 2 + 1];
    float4 o = {0.f, 0.f, 0.f, 0.f};
    for (int s = 0; s < ns; ++s) {
        const float4* y = reinterpret_cast<const float4*>(y_perm + (long)s * A_ * D_);
        float4 a = y[(long)p0 * (D_ / 4) + d4];
        float4 b = y[(long)p1 * (D_ / 4) + d4];
        o.x += a.x + b.x; o.y += a.y + b.y; o.z += a.z + b.z; o.w += a.w + b.w;
    }
    reinterpret_cast<float4*>(out + (long)t * D_)[d4] = o;
}

extern "C" void kernel_launch(void* const* d_in, const int* in_sizes, int n_in,
                              void* d_out, int out_size, void* d_ws, size_t ws_size,
                              hipStream_t stream) {
    const float* x        = (const float*)d_in[0];
    const float* router_W = (const float*)d_in[1];
    const float* W_in     = (const float*)d_in[2];
    const float* b_in     = (const float*)d_in[3];
    const float* W_out    = (const float*)d_in[4];
    const float* b_out    = (const float*)d_in[5];
    float* out = (float*)d_out;

    char* ws = (char*)d_ws;
    size_t off = 0;
    auto alloc = [&](size_t bytes) -> void* {
        void* p = ws + off;
        off += (bytes + 255) & ~(size_t)255;
        return p;
    };

    // phase-2 split-K factor gated on workspace for the partial buffers
    int ns = 1;
    if (ws_size >= (size_t)340 * 1024 * 1024)      ns = 4;
    else if (ws_size >= (size_t)272 * 1024 * 1024) ns = 2;

    char* ctrl = (char*)alloc(4096);
    int* counts_pad   = (int*)ctrl;                 // e*128 B apart
    float* probs_pad  = (float*)(ctrl + 1024);
    int* cursors_pad  = (int*)(ctrl + 2048);
    int* offsets      = (int*)(ctrl + 3072);
    int* tile_e       = (int*)(ctrl + 3200);
    int* tile_m       = (int*)(ctrl + 3584);
    int* n_tiles      = (int*)(ctrl + 3968);
    int* tok_e         = (int*)alloc((size_t)A_ * 4);
    float* tok_w       = (float*)alloc((size_t)A_ * 4);
    int* perm_token    = (int*)alloc((size_t)A_ * 4);
    float* perm_weight = (float*)alloc((size_t)A_ * 4);
    int* inv_pos       = (int*)alloc((size_t)A_ * 4);
    unsigned short* x_bf    = (unsigned short*)alloc((size_t)T_ * D_ * 2);
    unsigned short* w_in_t  = (unsigned short*)alloc((size_t)E_ * D_ * H_ * 2);
    unsigned short* w_out_t = (unsigned short*)alloc((size_t)E_ * D_ * H_ * 2);
    unsigned short* h_buf   = (unsigned short*)alloc((size_t)A_ * H_ * 2);
    float* y_perm           = (float*)alloc((size_t)ns * A_ * D_ * 4);

    hipMemsetAsync(ctrl, 0, 4096, stream);

    cast_x_kernel<<<(T_ * D_ / 4) / 256, 256, 0, stream>>>(x, x_bf);
    transpose_cast_kernel<<<dim3(H_ / 64, D_ / 64, E_), 256, 0, stream>>>(W_in, w_in_t, D_, H_);
    transpose_cast_kernel<<<dim3(D_ / 64, H_ / 64, E_), 256, 0, stream>>>(W_out, w_out_t, H_, D_);
    router_kernel<<<T_ / 16, 256, 0, stream>>>(x, router_W, tok_e, tok_w, counts_pad, probs_pad);
    offsets_aux_kernel<<<1, 64, 0, stream>>>(counts_pad, probs_pad, offsets,
                                             tile_e, tile_m, n_tiles, out + (out_size - 1));
    scatter_kernel<<<A_ / 256, 256, 0, stream>>>(tok_e, tok_w, offsets, cursors_pad,
                                                 perm_token, perm_weight, inv_pos);

    moe_gemm_p1<<<NTM_ * (H_ / 256), 512, 0, stream>>>(
        x_bf, w_in_t, b_in, offsets, tile_e, tile_m, n_tiles,
        perm_token, perm_weight, h_buf, y_perm);
    if (ns == 4) {
        moe_gemm_p2s4<<<NTM_ * (D_ / 256) * 4, 512, 0, stream>>>(
            h_buf, w_out_t, b_out, offsets, tile_e, tile_m, n_tiles,
            perm_token, perm_weight, h_buf, y_perm);
    } else if (ns == 2) {
        moe_gemm_p2s2<<<NTM_ * (D_ / 256) * 2, 512, 0, stream>>>(
            h_buf, w_out_t, b_out, offsets, tile_e, tile_m, n_tiles,
            perm_token, perm_weight, h_buf, y_perm);
    } else {
        moe_gemm_p2s1<<<NTM_ * (D_ / 256), 512, 0, stream>>>(
            h_buf, w_out_t, b_out, offsets, tile_e, tile_m, n_tiles,
            perm_token, perm_weight, h_buf, y_perm);
    }
    combine_kernel<<<T_, 256, 0, stream>>>(y_perm, inv_pos, out, ns);
}

// Round 6
// 603.330 us; speedup vs baseline: 1.1021x; 1.1021x over previous
//
#include <hip/hip_runtime.h>
#include <hip/hip_bf16.h>
#include <math.h>

#define B_ 4
#define S_ 1024
#define T_ (B_ * S_)      // 4096 tokens
#define D_ 1024
#define H_ 4096
#define E_ 8
#define K_ 2
#define A_ (T_ * K_)      // 8192 assignments
#define NTM_ 40           // max m-tiles at BM=256: 32 + 7 = 39 <= 40

typedef __bf16 bf16x8_t __attribute__((ext_vector_type(8)));
typedef float f32x4_t __attribute__((ext_vector_type(4)));
typedef unsigned short u16x8_t __attribute__((ext_vector_type(8)));
typedef unsigned short u16x4_t __attribute__((ext_vector_type(4)));

__device__ inline unsigned short f2bf(float f) {
    __hip_bfloat16 h = __float2bfloat16(f);
    return *reinterpret_cast<unsigned short*>(&h);
}

// fast GELU: A&S 7.1.26 erf poly, |err|~1e-5 absolute (bf16 quantum is 4e-3)
__device__ __forceinline__ float fast_gelu(float v) {
    float z = v * 0.70710678118654752440f;
    float az = fabsf(z);
    float t = __builtin_amdgcn_rcpf(1.0f + 0.3275911f * az);
    float poly = ((((1.061405429f * t - 1.453152027f) * t + 1.421413741f) * t
                   - 0.284496736f) * t + 0.254829592f) * t;
    float e = __expf(-az * az);
    float erfv = 1.0f - poly * e;
    erfv = (z < 0.0f) ? -erfv : erfv;
    return 0.5f * v * (1.0f + erfv);
}

// async global->LDS, 16B per lane. LDS dest = wave-uniform base + lane*16.
__device__ __forceinline__ void gl2lds16(const unsigned short* g, unsigned short* l) {
    auto* gp = reinterpret_cast<const __attribute__((address_space(1))) unsigned int*>(
        reinterpret_cast<uintptr_t>(g));
    auto* lp = reinterpret_cast<__attribute__((address_space(3))) unsigned int*>(
        reinterpret_cast<uintptr_t>(l));
    __builtin_amdgcn_global_load_lds(gp, lp, 16, 0, 0);
}

// ------- router (fused x->bf16 cast): 16 tokens/block, vectorized ---------
__global__ void router_kernel(const float* __restrict__ x, const float* __restrict__ rw,
                              unsigned short* __restrict__ xb,
                              int* __restrict__ tok_e, float* __restrict__ tok_w,
                              int* __restrict__ counts_pad, float* __restrict__ probs_pad) {
    __shared__ float s_probs[E_];
    __shared__ int s_counts[E_];
    const int tid = threadIdx.x;
    if (tid < E_) { s_probs[tid] = 0.f; s_counts[tid] = 0; }
    __syncthreads();
    const int wave = tid >> 6;
    const int lane = tid & 63;

    float wprob[E_];
    int wcount[E_];
#pragma unroll
    for (int e = 0; e < E_; ++e) { wprob[e] = 0.f; wcount[e] = 0; }

    for (int tt = 0; tt < 4; ++tt) {
        const int token = blockIdx.x * 16 + wave * 4 + tt;
        const float* xr = x + (long)token * D_;
        unsigned short* xbr = xb + (long)token * D_;
        float acc[E_];
#pragma unroll
        for (int e = 0; e < E_; ++e) acc[e] = 0.f;
#pragma unroll
        for (int i = 0; i < D_ / 256; ++i) {
            const int d0 = i * 256 + lane * 4;
            const float4 xv = *reinterpret_cast<const float4*>(xr + d0);
            u16x4_t pk;
            pk[0] = f2bf(xv.x); pk[1] = f2bf(xv.y);
            pk[2] = f2bf(xv.z); pk[3] = f2bf(xv.w);
            *reinterpret_cast<u16x4_t*>(xbr + d0) = pk;
            const float xs[4] = {xv.x, xv.y, xv.z, xv.w};
#pragma unroll
            for (int r = 0; r < 4; ++r) {
                const float4 w0 = *reinterpret_cast<const float4*>(rw + (long)(d0 + r) * E_);
                const float4 w1 = *reinterpret_cast<const float4*>(rw + (long)(d0 + r) * E_ + 4);
                acc[0] += xs[r] * w0.x; acc[1] += xs[r] * w0.y;
                acc[2] += xs[r] * w0.z; acc[3] += xs[r] * w0.w;
                acc[4] += xs[r] * w1.x; acc[5] += xs[r] * w1.y;
                acc[6] += xs[r] * w1.z; acc[7] += xs[r] * w1.w;
            }
        }
#pragma unroll
        for (int e = 0; e < E_; ++e) {
            for (int off = 32; off > 0; off >>= 1)
                acc[e] += __shfl_down(acc[e], off);
        }
        if (lane == 0) {
            float m = acc[0];
            for (int e = 1; e < E_; ++e) m = fmaxf(m, acc[e]);
            float p[E_], s = 0.f;
            for (int e = 0; e < E_; ++e) { p[e] = expf(acc[e] - m); s += p[e]; }
            float inv = 1.f / s;
            for (int e = 0; e < E_; ++e) { p[e] *= inv; wprob[e] += p[e]; }
            int i0 = 0;
            for (int e = 1; e < E_; ++e) if (p[e] > p[i0]) i0 = e;
            int i1 = (i0 == 0) ? 1 : 0;
            for (int e = 0; e < E_; ++e) if (e != i0 && p[e] > p[i1]) i1 = e;
            float w0 = p[i0], w1 = p[i1];
            float inv2 = 1.f / (w0 + w1 + 1e-8f);
            tok_e[token * 2] = i0;
            tok_e[token * 2 + 1] = i1;
            tok_w[token * 2] = w0 * inv2;
            tok_w[token * 2 + 1] = w1 * inv2;
            wcount[i0]++; wcount[i1]++;
        }
    }
    if (lane == 0) {
#pragma unroll
        for (int e = 0; e < E_; ++e) {
            atomicAdd(&s_probs[e], wprob[e]);
            if (wcount[e]) atomicAdd(&s_counts[e], wcount[e]);
        }
    }
    __syncthreads();
    if (tid < E_) {
        atomicAdd(&probs_pad[tid * 32], s_probs[tid]);
        if (s_counts[tid]) atomicAdd(&counts_pad[tid * 32], s_counts[tid]);
    }
}

// ------------- offsets + aux loss + compact tile table (BM=256) -----------
__global__ void offsets_aux_kernel(const int* __restrict__ counts_pad,
                                   const float* __restrict__ probs_pad,
                                   int* __restrict__ offsets,
                                   int* __restrict__ tile_e, int* __restrict__ tile_m,
                                   int* __restrict__ n_tiles, float* __restrict__ aux_out) {
    if (threadIdx.x == 0 && blockIdx.x == 0) {
        int run = 0, t = 0;
        for (int e = 0; e < E_; ++e) {
            int c = counts_pad[e * 32];
            offsets[e] = run;
            for (int m0 = 0; m0 < c; m0 += 256) {
                tile_e[t] = e; tile_m[t] = m0; ++t;
            }
            run += c;
        }
        offsets[E_] = run;
        *n_tiles = t;
        float aux = 0.f;
        for (int e = 0; e < E_; ++e)
            aux += (probs_pad[e * 32] / (float)T_) * ((float)counts_pad[e * 32] / (float)A_);
        *aux_out = (float)E_ * aux;
    }
}

// ---------------- scatter --------------------------------------------------
__global__ void scatter_kernel(const int* __restrict__ tok_e, const float* __restrict__ tok_w,
                               const int* __restrict__ offsets, int* __restrict__ cursors_pad,
                               int* __restrict__ perm_token, float* __restrict__ perm_weight,
                               int* __restrict__ inv_pos) {
    int i = blockIdx.x * blockDim.x + threadIdx.x;
    int lane = threadIdx.x & 63;
    int e = tok_e[i];
    float w = tok_w[i];
    unsigned long long bal[E_];
#pragma unroll
    for (int q = 0; q < E_; ++q) bal[q] = __ballot(e == q);
    unsigned long long below = (1ull << lane) - 1ull;
    int rank = __popcll(bal[e] & below);
    int base = 0;
    if (lane < E_) {
        int c = __popcll(bal[lane]);
        if (c) base = atomicAdd(&cursors_pad[lane * 32], c);
    }
    int mybase = __shfl(base, e);
    int pos = offsets[e] + mybase + rank;
    perm_token[pos] = i >> 1;
    perm_weight[pos] = w;
    inv_pos[i] = pos;
}

// -------- fp32 [R][C] -> bf16 [C][R] per expert, vectorized both sides ----
__global__ void transpose_cast_kernel(const float* __restrict__ in, unsigned short* __restrict__ out,
                                      int R, int C) {
    __shared__ float tile[64][65];
    const long e = blockIdx.z;
    const float* in_e = in + e * (long)R * C;
    unsigned short* out_e = out + e * (long)R * C;
    const int c0 = blockIdx.x * 64;
    const int r0 = blockIdx.y * 64;
    const int tid = threadIdx.x;
    const int c4 = (tid & 15) * 4;
    const int rb = tid >> 4;
#pragma unroll
    for (int i = 0; i < 4; ++i) {
        const int r = rb + i * 16;
        const float4 v = *reinterpret_cast<const float4*>(&in_e[(long)(r0 + r) * C + c0 + c4]);
        tile[r][c4] = v.x; tile[r][c4 + 1] = v.y; tile[r][c4 + 2] = v.z; tile[r][c4 + 3] = v.w;
    }
    __syncthreads();
    const int rs = (tid & 7) * 8;
    const int cb = tid >> 3;
#pragma unroll
    for (int i = 0; i < 2; ++i) {
        const int c = cb + i * 32;
        u16x8_t p;
#pragma unroll
        for (int j = 0; j < 8; ++j) p[j] = f2bf(tile[rs + j][c]);
        *reinterpret_cast<u16x8_t*>(&out_e[(long)(c0 + c) * R + r0 + rs]) = p;
    }
}

// ---- grouped GEMM: 256x256 tile, 1024 thr (16 waves of 64x64), BK=32, ----
// ---- 4-stage LDS ring (128 KB), 3-tile lookahead, counted vmcnt, 1 -------
// ---- RAW barrier/step. Step body is compiler-scheduled: plain ds_reads ---
// ---- + MFMAs (fine-grained lgkmcnt interleave, m97-style), with ONE ------
// ---- trailing lgkmcnt(0) before the barrier. That trailing wait is what --
// ---- makes the raw-barrier ring safe: all of this wave's reads of buf ----
// ---- t%4 are complete before it arrives at barrier t+1, and the restage --
// ---- of that buffer is issued only after barrier t+1 (post-barrier fence -
// ---- pins the gl_lds issue). vmcnt never drains mid-loop. ----------------
template <int PHASE, int NSPLIT>
__device__ __forceinline__ void gemm_body(const unsigned short* __restrict__ A_src,
                                const unsigned short* __restrict__ B_src,  // [E][N][K] bf16
                                const float* __restrict__ bias,            // [E][N]
                                const int* __restrict__ offsets,
                                const int* __restrict__ tile_e, const int* __restrict__ tile_m,
                                const int* __restrict__ p_ntiles,
                                const int* __restrict__ perm_token,
                                const float* __restrict__ perm_weight,
                                unsigned short* __restrict__ h_buf,
                                float* __restrict__ y_perm) {
    constexpr int Ksz  = (PHASE == 1) ? D_ : H_;
    constexpr int Kloc = Ksz / NSPLIT;
    constexpr int Nsz  = (PHASE == 1) ? H_ : D_;
    constexpr int NT   = Kloc / 32;                 // K-tiles
    constexpr int NTN  = Nsz / 256;

    // bijective XCD-chunked swizzle; mt fastest (B panel reuse in XCD L2)
    const int nwg = gridDim.x;
    const int id = blockIdx.x;
    const int q = nwg >> 3, r8 = nwg & 7;
    const int xcd = id & 7, sub = id >> 3;
    const int wg = (xcd < r8 ? xcd * (q + 1) : r8 * (q + 1) + (xcd - r8) * q) + sub;
    const int mt = wg % NTM_;
    if (mt >= *p_ntiles) return;
    const int rest = wg / NTM_;
    const int nt = rest % NTN;
    const int kh = rest / NTN;
    const int e = tile_e[mt];
    const int m0 = tile_m[mt];
    const int off_e = offsets[e];
    const int n_e = offsets[e + 1] - off_e;
    const int n0 = nt * 256;
    const long k_base = (long)kh * Kloc;

    // 4-stage ring: A 256x32 (16 KB) + B 256x32 (16 KB) per stage -> 128 KB
    __shared__ __attribute__((aligned(16))) unsigned short lds_a[4 * 8192];
    __shared__ __attribute__((aligned(16))) unsigned short lds_b[4 * 8192];

    const int tid = threadIdx.x;
    const int lane = tid & 63;
    const int wave = tid >> 6;          // 0..15
    const int wr = wave >> 2;           // 0..3 (64-row strip)
    const int wc = wave & 3;            // 0..3 (64-col strip)
    const int lrow = lane & 15;
    const int kg = lane >> 4;

    // staging: wave stages rows [wave*16, wave*16+16) of A and of B.
    // lane: row wave*16+(lane>>2), 16B chunk lane&3; source chunk XOR-swz.
    const int srow = lane >> 2;
    const int grow = wave * 16 + srow;
    const int sc = (lane & 3) ^ ((grow >> 1) & 3);
    const int m_loc = m0 + grow;
    const int m_cl = (m_loc < n_e) ? m_loc : (n_e - 1);
    const int spos = off_e + m_cl;
    long arow;
    if (PHASE == 1) arow = (long)perm_token[spos] * Ksz;
    else            arow = (long)spos * Ksz;
    const unsigned short* gA = A_src + arow + k_base + sc * 8;
    const unsigned short* gB = B_src + (long)e * Nsz * Ksz + (long)(n0 + grow) * Ksz + k_base + sc * 8;
    unsigned short* const la0 = lds_a + wave * 512;
    unsigned short* const lb0 = lds_b + wave * 512;

    // ds_read offsets (shorts): row-major [row][32], chunk = kg ^ ((row>>1)&3)
    int aoff[4], boff[4];
#pragma unroll
    for (int i = 0; i < 4; ++i) {
        const int r = wr * 64 + i * 16 + lrow;
        aoff[i] = r * 32 + ((kg ^ ((r >> 1) & 3)) * 8);
        const int c = wc * 64 + i * 16 + lrow;
        boff[i] = c * 32 + ((kg ^ ((c >> 1) & 3)) * 8);
    }

    f32x4_t acc[4][4];
#pragma unroll
    for (int i = 0; i < 4; ++i)
#pragma unroll
        for (int j = 0; j < 4; ++j) acc[i][j] = (f32x4_t){0.f, 0.f, 0.f, 0.f};

    // prologue: stage tiles 0,1,2 (6 instrs/wave in flight = 96 KB/CU)
#pragma unroll
    for (int tt = 0; tt < 3; ++tt) {
        gl2lds16(gA + tt * 32, la0 + tt * 8192);
        gl2lds16(gB + tt * 32, lb0 + tt * 8192);
    }

    for (int t = 0; t < NT; ++t) {
        // wait: tile t landed (newest <=2 tiles may stay in flight)
        if (t + 2 < NT)      asm volatile("s_waitcnt vmcnt(4)" ::: "memory");
        else if (t + 1 < NT) asm volatile("s_waitcnt vmcnt(2)" ::: "memory");
        else                 asm volatile("s_waitcnt vmcnt(0)" ::: "memory");
        __builtin_amdgcn_s_barrier();
        asm volatile("" ::: "memory");   // pin gl_lds issue after the barrier
        if (t + 3 < NT) {
            gl2lds16(gA + (t + 3) * 32, la0 + ((t + 3) & 3) * 8192);
            gl2lds16(gB + (t + 3) * 32, lb0 + ((t + 3) & 3) * 8192);
        }
        const unsigned short* la = lds_a + (t & 3) * 8192;
        const unsigned short* lb = lds_b + (t & 3) * 8192;
        bf16x8_t af[4], bf[4];
#pragma unroll
        for (int i = 0; i < 4; ++i) {
            af[i] = *reinterpret_cast<const bf16x8_t*>(la + aoff[i]);
            bf[i] = *reinterpret_cast<const bf16x8_t*>(lb + boff[i]);
        }
        // compiler-scheduled: fine-grained lgkmcnt interleaves reads & MFMAs
#pragma unroll
        for (int i = 0; i < 4; ++i)
#pragma unroll
            for (int j = 0; j < 4; ++j)
                acc[i][j] = __builtin_amdgcn_mfma_f32_16x16x32_bf16(af[i], bf[j], acc[i][j], 0, 0, 0);
        // all reads of buf t%4 done before crossing the next barrier
        asm volatile("s_waitcnt lgkmcnt(0)" ::: "memory");
    }

    // epilogue
    const float* bias_e = bias + (long)e * Nsz;
#pragma unroll
    for (int i = 0; i < 4; ++i) {
#pragma unroll
        for (int rq = 0; rq < 4; ++rq) {
            const int row_loc = wr * 64 + i * 16 + kg * 4 + rq;
            const int m_out = m0 + row_loc;
            if (m_out >= n_e) continue;
            const int pos = off_e + m_out;
            if (PHASE == 1) {
#pragma unroll
                for (int j = 0; j < 4; ++j) {
                    const int n = n0 + wc * 64 + j * 16 + lrow;
                    float v = acc[i][j][rq] + bias_e[n];
                    h_buf[(long)pos * Nsz + n] = f2bf(fast_gelu(v));
                }
            } else {
                float* yp = y_perm + (long)kh * ((long)A_ * D_);
                const float wgt = perm_weight[pos];
#pragma unroll
                for (int j = 0; j < 4; ++j) {
                    const int n = n0 + wc * 64 + j * 16 + lrow;
                    float v = acc[i][j][rq] + ((kh == 0) ? bias_e[n] : 0.f);
                    yp[(long)pos * Nsz + n] = v * wgt;
                }
            }
        }
    }
}

#define GEMM_ARGS const unsigned short* __restrict__ A_src, \
                  const unsigned short* __restrict__ B_src, \
                  const float* __restrict__ bias, \
                  const int* __restrict__ offsets, \
                  const int* __restrict__ tile_e, const int* __restrict__ tile_m, \
                  const int* __restrict__ p_ntiles, \
                  const int* __restrict__ perm_token, \
                  const float* __restrict__ perm_weight, \
                  unsigned short* __restrict__ h_buf, \
                  float* __restrict__ y_perm
#define GEMM_PASS A_src, B_src, bias, offsets, tile_e, tile_m, p_ntiles, \
                  perm_token, perm_weight, h_buf, y_perm

__launch_bounds__(1024, 4)
__global__ void moe_gemm_p1(GEMM_ARGS) { gemm_body<1, 1>(GEMM_PASS); }
__launch_bounds__(1024, 4)
__global__ void moe_gemm_p2s1(GEMM_ARGS) { gemm_body<2, 1>(GEMM_PASS); }
__launch_bounds__(1024, 4)
__global__ void moe_gemm_p2s2(GEMM_ARGS) { gemm_body<2, 2>(GEMM_PASS); }

// ---------------- combine: out[t] = sum over splits and the 2 positions ---
__global__ void combine_kernel(const float* __restrict__ y_perm, const int* __restrict__ inv_pos,
                               float* __restrict__ out, int ns) {
    int t = blockIdx.x;
    int d4 = threadIdx.x;                 // 0..255, float4 index (D_/4 = 256)
    int p0 = inv_pos[t * 2];
    int p1 = inv_pos[t * 2 + 1];
    float4 o = {0.f, 0.f, 0.f, 0.f};
    for (int s = 0; s < ns; ++s) {
        const float4* y = reinterpret_cast<const float4*>(y_perm + (long)s * A_ * D_);
        float4 a = y[(long)p0 * (D_ / 4) + d4];
        float4 b = y[(long)p1 * (D_ / 4) + d4];
        o.x += a.x + b.x; o.y += a.y + b.y; o.z += a.z + b.z; o.w += a.w + b.w;
    }
    reinterpret_cast<float4*>(out + (long)t * D_)[d4] = o;
}

extern "C" void kernel_launch(void* const* d_in, const int* in_sizes, int n_in,
                              void* d_out, int out_size, void* d_ws, size_t ws_size,
                              hipStream_t stream) {
    const float* x        = (const float*)d_in[0];
    const float* router_W = (const float*)d_in[1];
    const float* W_in     = (const float*)d_in[2];
    const float* b_in     = (const float*)d_in[3];
    const float* W_out    = (const float*)d_in[4];
    const float* b_out    = (const float*)d_in[5];
    float* out = (float*)d_out;

    char* ws = (char*)d_ws;
    size_t off = 0;
    auto alloc = [&](size_t bytes) -> void* {
        void* p = ws + off;
        off += (bytes + 255) & ~(size_t)255;
        return p;
    };

    // phase-2 split-K=2 gated on workspace for the second partial buffer
    const int ns = (ws_size >= (size_t)280 * 1024 * 1024) ? 2 : 1;

    char* ctrl = (char*)alloc(4096);
    int* counts_pad   = (int*)ctrl;                 // e*128 B apart
    float* probs_pad  = (float*)(ctrl + 1024);
    int* cursors_pad  = (int*)(ctrl + 2048);
    int* offsets      = (int*)(ctrl + 3072);
    int* tile_e       = (int*)(ctrl + 3200);
    int* tile_m       = (int*)(ctrl + 3584);
    int* n_tiles      = (int*)(ctrl + 3968);
    int* tok_e         = (int*)alloc((size_t)A_ * 4);
    float* tok_w       = (float*)alloc((size_t)A_ * 4);
    int* perm_token    = (int*)alloc((size_t)A_ * 4);
    float* perm_weight = (float*)alloc((size_t)A_ * 4);
    int* inv_pos       = (int*)alloc((size_t)A_ * 4);
    unsigned short* x_bf    = (unsigned short*)alloc((size_t)T_ * D_ * 2);
    unsigned short* w_in_t  = (unsigned short*)alloc((size_t)E_ * D_ * H_ * 2);
    unsigned short* w_out_t = (unsigned short*)alloc((size_t)E_ * D_ * H_ * 2);
    unsigned short* h_buf   = (unsigned short*)alloc((size_t)A_ * H_ * 2);
    float* y_perm           = (float*)alloc((size_t)ns * A_ * D_ * 4);

    hipMemsetAsync(ctrl, 0, 4096, stream);

    router_kernel<<<T_ / 16, 256, 0, stream>>>(x, router_W, x_bf, tok_e, tok_w,
                                               counts_pad, probs_pad);
    transpose_cast_kernel<<<dim3(H_ / 64, D_ / 64, E_), 256, 0, stream>>>(W_in, w_in_t, D_, H_);
    transpose_cast_kernel<<<dim3(D_ / 64, H_ / 64, E_), 256, 0, stream>>>(W_out, w_out_t, H_, D_);
    offsets_aux_kernel<<<1, 64, 0, stream>>>(counts_pad, probs_pad, offsets,
                                             tile_e, tile_m, n_tiles, out + (out_size - 1));
    scatter_kernel<<<A_ / 256, 256, 0, stream>>>(tok_e, tok_w, offsets, cursors_pad,
                                                 perm_token, perm_weight, inv_pos);

    moe_gemm_p1<<<NTM_ * (H_ / 256), 1024, 0, stream>>>(
        x_bf, w_in_t, b_in, offsets, tile_e, tile_m, n_tiles,
        perm_token, perm_weight, h_buf, y_perm);
    if (ns == 2) {
        moe_gemm_p2s2<<<NTM_ * (D_ / 256) * 2, 1024, 0, stream>>>(
            h_buf, w_out_t, b_out, offsets, tile_e, tile_m, n_tiles,
            perm_token, perm_weight, h_buf, y_perm);
    } else {
        moe_gemm_p2s1<<<NTM_ * (D_ / 256), 1024, 0, stream>>>(
            h_buf, w_out_t, b_out, offsets, tile_e, tile_m, n_tiles,
            perm_token, perm_weight, h_buf, y_perm);
    }
    combine_kernel<<<T_, 256, 0, stream>>>(y_perm, inv_pos, out, ns);
}